// Round 1
// baseline (59638.080 us; speedup 1.0000x reference)
//
#include <hip/hip_runtime.h>
#include <cstddef>

// Problem constants (match reference)
#define Bn  256
#define Tn  1024
#define Cn  128
#define Hn  256
#define WIN 24

// d_out layout: [B*T*H] output, then [B*H] final h, then [B*H] final c.
// We use the final-h slot as the live h_in buffer (it ends holding h_T because
// the last step writes plain h_new there), and the final-c slot as live c state.
// The skip ring buffer is simply out[:, t-24, :] read back from d_out.

__global__ __launch_bounds__(256) void init_state(
    const float* __restrict__ h0, const float* __restrict__ c0,
    float* __restrict__ hbuf, float* __restrict__ cbuf)
{
    int i = blockIdx.x * 256 + threadIdx.x;   // 0 .. B*H-1
    int u = i & (Hn - 1);
    hbuf[i] = h0[u];   // h_in for step 0 is just h0 (mask=0)
    cbuf[i] = c0[u];
}

__global__ __launch_bounds__(256) void lstm_step(
    const float* __restrict__ x,       // [B,T,C]
    const float* __restrict__ W_ih,    // [4H,C]
    const float* __restrict__ W_hh,    // [4H,H]
    const float* __restrict__ b_ih,    // [4H]
    const float* __restrict__ b_hh,    // [4H]
    const float* __restrict__ W_skip,  // [H,H]
    const float* __restrict__ b_skip,  // [H]
    float* __restrict__ outp,          // [B,T,H]
    float* __restrict__ hbuf,          // [B,H] h_in for this step (overwritten with next step's h_in)
    float* __restrict__ cbuf,          // [B,H] c state
    int t)
{
    __shared__ float s_hin[16][Hn + 1];   // +1 pad: kill 16-way bank conflict on column reads
    __shared__ float s_x[16][Cn + 1];
    __shared__ float s_g[16][16];

    const int ug   = blockIdx.x;   // 0..63 : unit group (4 hidden units)
    const int rg   = blockIdx.y;   // 0..15 : row group (16 batch rows)
    const int tid  = threadIdx.x;  // 0..255
    const int row0 = rg * 16;

    // Stage h_in[16][256] and x_t[16][128] into LDS
    for (int i = tid; i < 16 * Hn; i += 256) {
        int r = i >> 8, k = i & (Hn - 1);
        s_hin[r][k] = hbuf[(row0 + r) * Hn + k];
    }
    for (int i = tid; i < 16 * Cn; i += 256) {
        int r = i >> 7, k = i & (Cn - 1);
        s_x[r][k] = x[(size_t)(row0 + r) * (Tn * Cn) + (size_t)t * Cn + k];
    }
    __syncthreads();

    // Each thread: one gate pre-activation. tid -> (row r, gate g, local unit ul)
    const int r    = tid >> 4;         // 0..15
    const int s    = tid & 15;
    const int ul   = s & 3;
    const int g    = s >> 2;           // 0:i 1:f 2:g 3:o (torch order)
    const int unit = (ug << 2) | ul;   // 0..255
    const int wrow = g * Hn + unit;    // row of W_ih / W_hh

    float acc = b_ih[wrow] + b_hh[wrow];
    {
        const float* wih = W_ih + (size_t)wrow * Cn;
        #pragma unroll 8
        for (int k = 0; k < Cn; ++k) acc += s_x[r][k] * wih[k];
        const float* whh = W_hh + (size_t)wrow * Hn;
        #pragma unroll 8
        for (int k = 0; k < Hn; ++k) acc += s_hin[r][k] * whh[k];
    }
    s_g[r][s] = acc;
    __syncthreads();   // (B) all dot-products done; s_hin free for reuse

    // Elementwise LSTM cell: 64 threads handle [16 rows x 4 units]
    const int r2    = tid >> 2;
    const int ul2   = tid & 3;
    const int unit2 = (ug << 2) | ul2;
    float h_new = 0.f;
    if (tid < 64) {
        float gi = s_g[r2][ul2];
        float gf = s_g[r2][4 + ul2];
        float gg = s_g[r2][8 + ul2];
        float go = s_g[r2][12 + ul2];
        float c_old = cbuf[(row0 + r2) * Hn + unit2];
        float si = 1.f / (1.f + expf(-gi));
        float sf = 1.f / (1.f + expf(-gf));
        float so = 1.f / (1.f + expf(-go));
        float c_new = sf * c_old + si * tanhf(gg);
        h_new = so * tanhf(c_new);
        cbuf[(row0 + r2) * Hn + unit2] = c_new;
        outp[(size_t)(row0 + r2) * (Tn * Hn) + (size_t)t * Hn + unit2] = h_new;
    }

    // Prepare next step's h_in = h_new + mask*(out[:, nt-24, :] @ W_skip^T + b_skip)
    const int nt = t + 1;
    if (nt < Tn) {
        if (nt >= WIN) {
            // reload ring slice (h_{nt-24}) into s_hin; safe: dot reads done at (B)
            for (int i = tid; i < 16 * Hn; i += 256) {
                int rr = i >> 8, k = i & (Hn - 1);
                s_hin[rr][k] = outp[(size_t)(row0 + rr) * (Tn * Hn) + (size_t)(nt - WIN) * Hn + k];
            }
            __syncthreads();   // (C) ring staged; also guards s_g reuse below
            // partial skip dot: thread (r, unit, k-quarter g)
            const float* wsk = W_skip + (size_t)unit * Hn;
            float p = 0.f;
            const int k0 = g << 6;
            #pragma unroll 8
            for (int k = k0; k < k0 + 64; ++k) p += s_hin[r][k] * wsk[k];
            s_g[r][s] = p;
            __syncthreads();   // (D)
        }
        if (tid < 64) {
            float hin = h_new;
            if (nt >= WIN) {
                hin += s_g[r2][ul2] + s_g[r2][4 + ul2] + s_g[r2][8 + ul2]
                     + s_g[r2][12 + ul2] + b_skip[unit2];
            }
            hbuf[(row0 + r2) * Hn + unit2] = hin;
        }
    } else {
        // last step: h slot must hold final h = h_new
        if (tid < 64) hbuf[(row0 + r2) * Hn + unit2] = h_new;
    }
}

extern "C" void kernel_launch(void* const* d_in, const int* in_sizes, int n_in,
                              void* d_out, int out_size, void* d_ws, size_t ws_size,
                              hipStream_t stream)
{
    const float* x      = (const float*)d_in[0];
    const float* W_ih   = (const float*)d_in[1];
    const float* W_hh   = (const float*)d_in[2];
    const float* b_ih   = (const float*)d_in[3];
    const float* b_hh   = (const float*)d_in[4];
    const float* W_skip = (const float*)d_in[5];
    const float* b_skip = (const float*)d_in[6];
    const float* h0     = (const float*)d_in[7];
    const float* c0     = (const float*)d_in[8];

    float* outp = (float*)d_out;
    float* hbuf = outp + (size_t)Bn * Tn * Hn;   // final-h slot = live h_in buffer
    float* cbuf = hbuf + (size_t)Bn * Hn;        // final-c slot = live c state

    init_state<<<dim3((Bn * Hn) / 256), 256, 0, stream>>>(h0, c0, hbuf, cbuf);

    for (int t = 0; t < Tn; ++t) {
        lstm_step<<<dim3(64, 16), 256, 0, stream>>>(
            x, W_ih, W_hh, b_ih, b_hh, W_skip, b_skip, outp, hbuf, cbuf, t);
    }
}

// Round 2
// 16424.515 us; speedup vs baseline: 3.6310x; 3.6310x over previous
//
#include <hip/hip_runtime.h>
#include <cstddef>

#define Bn  256
#define Tn  1024
#define Cn  128
#define Hn  256
#define WIN 24

#define NRG 16   // row groups
#define NUG 16   // unit groups
#define RPB 16   // rows per block
#define UPB 16   // units per block
#define KT  48   // k-range per k-group (384/8)

struct __align__(64) Flag { int v; int pad[15]; };
__device__ Flag  g_flag[NRG][NUG];
__device__ float g_hx[2][Bn][Hn];   // h_in exchange, double-buffered

__global__ __launch_bounds__(256) void init_sync(const float* __restrict__ h0) {
    int i = blockIdx.x * 256 + threadIdx.x;       // 0 .. 65535
    g_hx[0][i >> 8][i & 255] = h0[i & 255];       // h_in for t=0 is h0 (mask=0)
    if (i < NRG * NUG) g_flag[i >> 4][i & 15].v = 0;
}

__global__ __launch_bounds__(256, 1) void lstm_persist(
    const float* __restrict__ x,
    const float* __restrict__ W_ih, const float* __restrict__ W_hh,
    const float* __restrict__ b_ih, const float* __restrict__ b_hh,
    const float* __restrict__ W_skip, const float* __restrict__ b_skip,
    const float* __restrict__ c0,
    float* __restrict__ outp, float* __restrict__ hbuf, float* __restrict__ cbuf)
{
    // LDS total = 82752 B  (> 81920 -> exactly 1 block/CU -> 256 blocks co-resident)
    __shared__ float s_in[RPB][392];      // [row][k]: k 0..127 = x_t, 128..383 = h_in
    __shared__ float s_red[4][32][45];    // cross-wave partial sums
    __shared__ float s_h24[RPB][268];     // h_{t-23} tile for skip matmul
    __shared__ float s_wsk[UPB][268];     // W_skip rows for our 16 units
    __shared__ float s_bias[64];          // b_ih+b_hh for our 64 gate-rows
    __shared__ float s_bskip[UPB];

    const int tid = threadIdx.x;
    const int bid = blockIdx.x;
    const int rg = bid >> 4, ug = bid & 15;
    const int row0 = rg * RPB, u0 = ug * UPB;

    const int sr = tid >> 4, su = tid & 15;   // staging / cell / skip mapping
    const int kg = tid >> 5, nq = tid & 31;   // GEMM mapping: k-group, gate-pair
    const int wv = tid >> 6;                  // wave id

    // ---- once: weight slice into registers (2 gate-rows x 48 k) ----
    float w0[KT], w1[KT];
    {
        const int wl0 = nq * 2, wl1 = wl0 + 1;
        const int R0 = (wl0 >> 4) * Hn + u0 + (wl0 & 15);
        const int R1 = (wl1 >> 4) * Hn + u0 + (wl1 & 15);
        const int kb = kg * KT;
        #pragma unroll
        for (int kk = 0; kk < KT; ++kk) {
            int k = kb + kk;
            w0[kk] = (k < Cn) ? W_ih[(size_t)R0 * Cn + k] : W_hh[(size_t)R0 * Hn + (k - Cn)];
            w1[kk] = (k < Cn) ? W_ih[(size_t)R1 * Cn + k] : W_hh[(size_t)R1 * Hn + (k - Cn)];
        }
    }
    // ---- once: LDS-resident W_skip slice, biases ----
    {
        const float* wr = W_skip + (size_t)(u0 + sr) * Hn;
        #pragma unroll
        for (int c = 0; c < 4; ++c)
            *(float4*)&s_wsk[sr][c * 64 + su * 4] = *(const float4*)&wr[c * 64 + su * 4];
        if (tid < 64) {
            int R = (tid >> 4) * Hn + u0 + (tid & 15);
            s_bias[tid] = b_ih[R] + b_hh[R];
        }
        if (tid < 16) s_bskip[tid] = b_skip[u0 + tid];
    }
    float c_reg = c0[u0 + su];

    // prefetch x[t=0]
    float4 xp0, xp1;
    {
        const float* xr = x + (size_t)(row0 + sr) * (Tn * Cn);
        xp0 = *(const float4*)&xr[su * 4];
        xp1 = *(const float4*)&xr[64 + su * 4];
    }
    __syncthreads();

    for (int t = 0; t < Tn; ++t) {
        // 1. wait for all 16 peers of our row-group to publish h_in for step t
        if (tid < NUG) {
            while (__hip_atomic_load(&g_flag[rg][tid].v, __ATOMIC_RELAXED,
                                     __HIP_MEMORY_SCOPE_AGENT) < t)
                __builtin_amdgcn_s_sleep(1);
            (void)__hip_atomic_load(&g_flag[rg][tid].v, __ATOMIC_ACQUIRE,
                                    __HIP_MEMORY_SCOPE_AGENT);
        }
        __syncthreads();

        // 2. stage s_in = [x_t | h_in]; prefetch x[t+1]
        *(float4*)&s_in[sr][su * 4]      = xp0;
        *(float4*)&s_in[sr][64 + su * 4] = xp1;
        {
            const float* hxs = g_hx[t & 1][row0 + sr];
            #pragma unroll
            for (int c = 0; c < 4; ++c)
                *(float4*)&s_in[sr][Cn + c * 64 + su * 4] = *(const float4*)&hxs[c * 64 + su * 4];
        }
        if (t + 1 < Tn) {
            const float* xr = x + (size_t)(row0 + sr) * (Tn * Cn) + (size_t)(t + 1) * Cn;
            xp0 = *(const float4*)&xr[su * 4];
            xp1 = *(const float4*)&xr[64 + su * 4];
        }
        __syncthreads();

        // 3. gates partial GEMM: 16 rows x 2 gate-rows x 48 k, weights in regs
        float a0[RPB], a1[RPB];
        #pragma unroll
        for (int r = 0; r < RPB; ++r) { a0[r] = 0.f; a1[r] = 0.f; }
        {
            const int kb = kg * KT;
            #pragma unroll
            for (int kk = 0; kk < KT; kk += 4) {
                #pragma unroll
                for (int r = 0; r < RPB; ++r) {
                    float4 hv = *(const float4*)&s_in[r][kb + kk];
                    a0[r] = fmaf(hv.x, w0[kk],     a0[r]);
                    a0[r] = fmaf(hv.y, w0[kk + 1], a0[r]);
                    a0[r] = fmaf(hv.z, w0[kk + 2], a0[r]);
                    a0[r] = fmaf(hv.w, w0[kk + 3], a0[r]);
                    a1[r] = fmaf(hv.x, w1[kk],     a1[r]);
                    a1[r] = fmaf(hv.y, w1[kk + 1], a1[r]);
                    a1[r] = fmaf(hv.z, w1[kk + 2], a1[r]);
                    a1[r] = fmaf(hv.w, w1[kk + 3], a1[r]);
                }
            }
        }

        // 4. reduce 8 k-partials: xor-32 in wave, then LDS across 4 waves
        #pragma unroll
        for (int r = 0; r < RPB; ++r) {
            a0[r] += __shfl_xor(a0[r], 32, 64);
            a1[r] += __shfl_xor(a1[r], 32, 64);
        }
        if ((tid & 32) == 0) {
            #pragma unroll
            for (int r = 0; r < RPB; ++r) {
                s_red[wv][nq][r * 2]     = a0[r];
                s_red[wv][nq][r * 2 + 1] = a1[r];
            }
        }
        __syncthreads();

        // 5. cell update: thread (sr, su) owns (row row0+sr, unit u0+su)
        float gate[4];
        #pragma unroll
        for (int g = 0; g < 4; ++g) {
            int wl = g * 16 + su;
            int q = wl >> 1, j = wl & 1;
            float v = s_bias[wl];
            v += s_red[0][q][sr * 2 + j];
            v += s_red[1][q][sr * 2 + j];
            v += s_red[2][q][sr * 2 + j];
            v += s_red[3][q][sr * 2 + j];
            gate[g] = v;
        }
        float si = 1.f / (1.f + expf(-gate[0]));
        float sf = 1.f / (1.f + expf(-gate[1]));
        float gt = tanhf(gate[2]);
        float so = 1.f / (1.f + expf(-gate[3]));
        c_reg = sf * c_reg + si * gt;
        float hn = so * tanhf(c_reg);
        outp[(size_t)(row0 + sr) * (Tn * Hn) + (size_t)t * Hn + u0 + su] = hn;

        if (t < Tn - 1) {
            float hin = hn;
            if (t >= WIN - 1) {
                // stage h_{t-23} (ring = out buffer itself), visible via per-step acquires
                const float* hsrc = outp + (size_t)(row0 + sr) * (Tn * Hn)
                                         + (size_t)(t - (WIN - 1)) * Hn;
                #pragma unroll
                for (int c = 0; c < 4; ++c)
                    *(float4*)&s_h24[sr][c * 64 + su * 4] = *(const float4*)&hsrc[c * 64 + su * 4];
                __syncthreads();
                float sk = 0.f;
                #pragma unroll
                for (int k = 0; k < Hn; k += 4) {
                    float4 hv  = *(const float4*)&s_h24[sr][k];
                    float4 wv4 = *(const float4*)&s_wsk[su][k];
                    sk = fmaf(hv.x, wv4.x, sk);
                    sk = fmaf(hv.y, wv4.y, sk);
                    sk = fmaf(hv.z, wv4.z, sk);
                    sk = fmaf(hv.w, wv4.w, sk);
                }
                hin += sk + s_bskip[su];
            }
            // 6. publish h_in for step t+1, release flag
            g_hx[(t + 1) & 1][row0 + sr][u0 + su] = hin;
            __syncthreads();
            if (tid == 0)
                __hip_atomic_store(&g_flag[rg][ug].v, t + 1, __ATOMIC_RELEASE,
                                   __HIP_MEMORY_SCOPE_AGENT);
        } else {
            hbuf[(size_t)(row0 + sr) * Hn + u0 + su] = hn;
            cbuf[(size_t)(row0 + sr) * Hn + u0 + su] = c_reg;
        }
    }
}

extern "C" void kernel_launch(void* const* d_in, const int* in_sizes, int n_in,
                              void* d_out, int out_size, void* d_ws, size_t ws_size,
                              hipStream_t stream)
{
    const float* x      = (const float*)d_in[0];
    const float* W_ih   = (const float*)d_in[1];
    const float* W_hh   = (const float*)d_in[2];
    const float* b_ih   = (const float*)d_in[3];
    const float* b_hh   = (const float*)d_in[4];
    const float* W_skip = (const float*)d_in[5];
    const float* b_skip = (const float*)d_in[6];
    const float* h0     = (const float*)d_in[7];
    const float* c0     = (const float*)d_in[8];

    float* outp = (float*)d_out;
    float* hbuf = outp + (size_t)Bn * Tn * Hn;
    float* cbuf = hbuf + (size_t)Bn * Hn;

    init_sync<<<256, 256, 0, stream>>>(h0);
    lstm_persist<<<256, 256, 0, stream>>>(x, W_ih, W_hh, b_ih, b_hh,
                                          W_skip, b_skip, c0, outp, hbuf, cbuf);
}

// Round 3
// 8149.879 us; speedup vs baseline: 7.3177x; 2.0153x over previous
//
#include <hip/hip_runtime.h>
#include <cstddef>

#define Bn  256
#define Tn  1024
#define Cn  128
#define Hn  256
#define WIN 24

#define NRG 16   // row groups
#define NUG 16   // unit groups
#define RPB 16   // rows per block
#define UPB 16   // units per block
#define KT  48   // k-range per k-group (384/8)

#define AGENT __HIP_MEMORY_SCOPE_AGENT
#define RLX   __ATOMIC_RELAXED

struct __align__(64) Flag { int v; int pad[15]; };
__device__ Flag  g_flag[NRG][NUG];
__device__ float g_hx[2][Bn][Hn];   // h_in exchange, double-buffered

__global__ __launch_bounds__(256) void init_sync(const float* __restrict__ h0) {
    int i = blockIdx.x * 256 + threadIdx.x;       // 0 .. 65535
    g_hx[0][i >> 8][i & 255] = h0[i & 255];       // h_in for t=0 is h0 (mask=0)
    if (i < NRG * NUG) g_flag[i >> 4][i & 15].v = 0;
    // plain stores: kernel-end writeback makes them visible to sc1 readers
}

__global__ __launch_bounds__(256, 1) void lstm_persist(
    const float* __restrict__ x,
    const float* __restrict__ W_ih, const float* __restrict__ W_hh,
    const float* __restrict__ b_ih, const float* __restrict__ b_hh,
    const float* __restrict__ W_skip, const float* __restrict__ b_skip,
    const float* __restrict__ c0,
    float* __restrict__ outp, float* __restrict__ hbuf, float* __restrict__ cbuf)
{
    // LDS total = 82752 B (> 81920 -> exactly 1 block/CU -> all 256 blocks co-resident)
    __shared__ float s_in[RPB][392];      // [row][k]: 0..127 x_t, 128..383 h_in
    __shared__ float s_red[4][32][45];    // cross-wave partial sums
    __shared__ float s_h24[RPB][268];     // h_{t-23} tile for skip matmul
    __shared__ float s_wsk[UPB][268];     // W_skip rows for our 16 units
    __shared__ float s_bias[64];
    __shared__ float s_bskip[UPB];

    const int tid = threadIdx.x;
    const int bid = blockIdx.x;
    const int rg = bid >> 4, ug = bid & 15;
    const int row0 = rg * RPB, u0 = ug * UPB;

    const int sr = tid >> 4, su = tid & 15;   // staging / cell / skip mapping
    const int kg = tid >> 5, nq = tid & 31;   // GEMM mapping
    const int wv = tid >> 6;                  // wave id

    // ---- once: weight slice into registers (2 gate-rows x 48 k) ----
    float w0[KT], w1[KT];
    {
        const int wl0 = nq * 2, wl1 = wl0 + 1;
        const int R0 = (wl0 >> 4) * Hn + u0 + (wl0 & 15);
        const int R1 = (wl1 >> 4) * Hn + u0 + (wl1 & 15);
        const int kb = kg * KT;
        #pragma unroll
        for (int kk = 0; kk < KT; ++kk) {
            int k = kb + kk;
            w0[kk] = (k < Cn) ? W_ih[(size_t)R0 * Cn + k] : W_hh[(size_t)R0 * Hn + (k - Cn)];
            w1[kk] = (k < Cn) ? W_ih[(size_t)R1 * Cn + k] : W_hh[(size_t)R1 * Hn + (k - Cn)];
        }
    }
    {
        const float* wr = W_skip + (size_t)(u0 + sr) * Hn;
        #pragma unroll
        for (int c = 0; c < 4; ++c)
            *(float4*)&s_wsk[sr][c * 64 + su * 4] = *(const float4*)&wr[c * 64 + su * 4];
        if (tid < 64) {
            int R = (tid >> 4) * Hn + u0 + (tid & 15);
            s_bias[tid] = b_ih[R] + b_hh[R];
        }
        if (tid < 16) s_bskip[tid] = b_skip[u0 + tid];
    }
    float c_reg = c0[u0 + su];

    // prefetch x[t=0]
    float4 xp0, xp1;
    {
        const float* xr = x + (size_t)(row0 + sr) * (Tn * Cn);
        xp0 = *(const float4*)&xr[su * 4];
        xp1 = *(const float4*)&xr[64 + su * 4];
    }
    __syncthreads();

    for (int t = 0; t < Tn; ++t) {
        // 1. wait for all 16 peers of our row-group (relaxed sc1 polls, no cache inv)
        if (tid < NUG) {
            int* fp = &g_flag[rg][tid].v;
            while (__hip_atomic_load(fp, RLX, AGENT) < t)
                __builtin_amdgcn_s_sleep(1);
        }
        __syncthreads();

        // 2. stage s_in = [x_t | h_in]; prefetch x[t+1]
        *(float4*)&s_in[sr][su * 4]      = xp0;
        *(float4*)&s_in[sr][64 + su * 4] = xp1;
        {
            float hv[16];
            float* hxs = &g_hx[t & 1][row0 + sr][0];
            #pragma unroll
            for (int c = 0; c < 16; ++c)
                hv[c] = __hip_atomic_load(&hxs[su + 16 * c], RLX, AGENT);
            #pragma unroll
            for (int c = 0; c < 16; ++c)
                s_in[sr][Cn + su + 16 * c] = hv[c];
        }
        if (t + 1 < Tn) {
            const float* xr = x + (size_t)(row0 + sr) * (Tn * Cn) + (size_t)(t + 1) * Cn;
            xp0 = *(const float4*)&xr[su * 4];
            xp1 = *(const float4*)&xr[64 + su * 4];
        }
        // issue t-23 ring loads now; values consumed after the GEMM (latency hidden)
        float rv[16];
        const bool do_ring = (t >= WIN - 1) && (t < Tn - 1);
        if (do_ring) {
            const float* hsrc = outp + (size_t)(row0 + sr) * (Tn * Hn)
                                     + (size_t)(t - (WIN - 1)) * Hn;
            #pragma unroll
            for (int c = 0; c < 16; ++c)
                rv[c] = __hip_atomic_load((float*)&hsrc[su + 16 * c], RLX, AGENT);
        }
        __syncthreads();

        // 3. gates partial GEMM: 16 rows x 2 gate-rows x 48 k, weights in regs
        float a0[RPB], a1[RPB];
        #pragma unroll
        for (int r = 0; r < RPB; ++r) { a0[r] = 0.f; a1[r] = 0.f; }
        {
            const int kb = kg * KT;
            #pragma unroll
            for (int kk = 0; kk < KT; kk += 4) {
                #pragma unroll
                for (int r = 0; r < RPB; ++r) {
                    float4 hv = *(const float4*)&s_in[r][kb + kk];
                    a0[r] = fmaf(hv.x, w0[kk],     a0[r]);
                    a0[r] = fmaf(hv.y, w0[kk + 1], a0[r]);
                    a0[r] = fmaf(hv.z, w0[kk + 2], a0[r]);
                    a0[r] = fmaf(hv.w, w0[kk + 3], a0[r]);
                    a1[r] = fmaf(hv.x, w1[kk],     a1[r]);
                    a1[r] = fmaf(hv.y, w1[kk + 1], a1[r]);
                    a1[r] = fmaf(hv.z, w1[kk + 2], a1[r]);
                    a1[r] = fmaf(hv.w, w1[kk + 3], a1[r]);
                }
            }
        }

        // 4. reduce 8 k-partials
        #pragma unroll
        for (int r = 0; r < RPB; ++r) {
            a0[r] += __shfl_xor(a0[r], 32, 64);
            a1[r] += __shfl_xor(a1[r], 32, 64);
        }
        if ((tid & 32) == 0) {
            #pragma unroll
            for (int r = 0; r < RPB; ++r) {
                s_red[wv][nq][r * 2]     = a0[r];
                s_red[wv][nq][r * 2 + 1] = a1[r];
            }
        }
        __syncthreads();

        // 5. cell update: thread (sr, su) owns (row row0+sr, unit u0+su)
        float gate[4];
        #pragma unroll
        for (int g = 0; g < 4; ++g) {
            int wl = g * 16 + su;
            int q = wl >> 1, j = wl & 1;
            float v = s_bias[wl];
            v += s_red[0][q][sr * 2 + j];
            v += s_red[1][q][sr * 2 + j];
            v += s_red[2][q][sr * 2 + j];
            v += s_red[3][q][sr * 2 + j];
            gate[g] = v;
        }
        float si = 1.f / (1.f + expf(-gate[0]));
        float sf = 1.f / (1.f + expf(-gate[1]));
        float gt = tanhf(gate[2]);
        float so = 1.f / (1.f + expf(-gate[3]));
        c_reg = sf * c_reg + si * gt;
        float hn = so * tanhf(c_reg);
        // write-through (sc1) so peers' ring reads are coherent without cache flushes
        __hip_atomic_store(&outp[(size_t)(row0 + sr) * (Tn * Hn) + (size_t)t * Hn + u0 + su],
                           hn, RLX, AGENT);

        if (t < Tn - 1) {
            float hin = hn;
            if (t >= WIN - 1) {
                #pragma unroll
                for (int c = 0; c < 16; ++c)
                    s_h24[sr][su + 16 * c] = rv[c];
                __syncthreads();
                float sk = 0.f;
                #pragma unroll
                for (int k = 0; k < Hn; k += 4) {
                    float4 hv  = *(const float4*)&s_h24[sr][k];
                    float4 wv4 = *(const float4*)&s_wsk[su][k];
                    sk = fmaf(hv.x, wv4.x, sk);
                    sk = fmaf(hv.y, wv4.y, sk);
                    sk = fmaf(hv.z, wv4.z, sk);
                    sk = fmaf(hv.w, wv4.w, sk);
                }
                hin += sk + s_bskip[su];
            }
            // 6. publish h_in for t+1 (sc1), ack at coherence point, then flag
            __hip_atomic_store(&g_hx[(t + 1) & 1][row0 + sr][u0 + su], hin, RLX, AGENT);
            asm volatile("s_waitcnt vmcnt(0)" ::: "memory");
            __syncthreads();
            if (tid == 0)
                __hip_atomic_store(&g_flag[rg][ug].v, t + 1, RLX, AGENT);
        } else {
            hbuf[(size_t)(row0 + sr) * Hn + u0 + su] = hn;
            cbuf[(size_t)(row0 + sr) * Hn + u0 + su] = c_reg;
        }
    }
}

extern "C" void kernel_launch(void* const* d_in, const int* in_sizes, int n_in,
                              void* d_out, int out_size, void* d_ws, size_t ws_size,
                              hipStream_t stream)
{
    const float* x      = (const float*)d_in[0];
    const float* W_ih   = (const float*)d_in[1];
    const float* W_hh   = (const float*)d_in[2];
    const float* b_ih   = (const float*)d_in[3];
    const float* b_hh   = (const float*)d_in[4];
    const float* W_skip = (const float*)d_in[5];
    const float* b_skip = (const float*)d_in[6];
    const float* h0     = (const float*)d_in[7];
    const float* c0     = (const float*)d_in[8];

    float* outp = (float*)d_out;
    float* hbuf = outp + (size_t)Bn * Tn * Hn;
    float* cbuf = hbuf + (size_t)Bn * Hn;

    init_sync<<<256, 256, 0, stream>>>(h0);
    lstm_persist<<<256, 256, 0, stream>>>(x, W_ih, W_hh, b_ih, b_hh,
                                          W_skip, b_skip, c0, outp, hbuf, cbuf);
}

// Round 4
// 7783.379 us; speedup vs baseline: 7.6622x; 1.0471x over previous
//
#include <hip/hip_runtime.h>
#include <cstddef>

#define Bn  256
#define Tn  1024
#define Cn  128
#define Hn  256
#define WIN 24

#define NRG 16   // row groups
#define NUG 16   // unit groups
#define RPB 16   // rows per block
#define UPB 16   // units per block

#define AGENT __HIP_MEMORY_SCOPE_AGENT
#define RLX   __ATOMIC_RELAXED

struct __align__(64) Flag { int v; int pad[15]; };
__device__ Flag  g_flag[NRG][NUG];
__device__ float g_hx[2][Bn][Hn];   // h_in exchange, double-buffered

__global__ __launch_bounds__(256) void init_sync(const float* __restrict__ h0) {
    int i = blockIdx.x * 256 + threadIdx.x;       // 0 .. 65535
    g_hx[0][i >> 8][i & 255] = h0[i & 255];       // h_in for t=0 is h0 (mask=0)
    if (i < NRG * NUG) g_flag[i >> 4][i & 15].v = 0;
}

__global__ __launch_bounds__(256, 1) void lstm_persist(
    const float* __restrict__ x,
    const float* __restrict__ W_ih, const float* __restrict__ W_hh,
    const float* __restrict__ b_ih, const float* __restrict__ b_hh,
    const float* __restrict__ W_skip, const float* __restrict__ b_skip,
    const float* __restrict__ c0,
    float* __restrict__ outp, float* __restrict__ hbuf, float* __restrict__ cbuf)
{
    // LDS 82,752 B (>81,920) -> exactly 1 block/CU -> all 256 blocks co-resident
    __shared__ float s_in[RPB][392];      // [row][k]: 0..127 x_t, 128..383 h_in
    __shared__ float s_red[4][32][45];    // cross-wave partial sums
    __shared__ float s_h24[RPB][268];     // h_{t-23} tile for skip matmul
    __shared__ float s_wsk[UPB][268];     // W_skip rows for our 16 units
    __shared__ float s_bias[64];
    __shared__ float s_bskip[UPB];

    const int tid = threadIdx.x;
    // XCD swizzle: put each row-group's 16 blocks on ONE XCD so their
    // shared x rows dedupe in that XCD's L2. (dispatch round-robins bid%8)
    const int xcd = blockIdx.x & 7, slot = blockIdx.x >> 3;   // slot 0..31
    const int rg = (xcd << 1) | (slot >> 4), ug = slot & 15;
    const int row0 = rg * RPB, u0 = ug * UPB;

    const int sr = tid >> 4, su = tid & 15;   // staging / cell / skip mapping
    const int kg = tid >> 5, nq = tid & 31;   // GEMM mapping: k-group, gate-pair
    const int wv = tid >> 6;                  // wave id

    // ---- once: weight slices into registers ----
    // gate-row pair (2nq, 2nq+1); x-part k slice [kg*16,+16), h-part [kg*32,+32)
    float wx0[16], wx1[16], wh0[32], wh1[32];
    {
        const int wl0 = nq * 2, wl1 = wl0 + 1;
        const int R0 = (wl0 >> 4) * Hn + u0 + (wl0 & 15);
        const int R1 = (wl1 >> 4) * Hn + u0 + (wl1 & 15);
        const int kbx = kg * 16, kbh = kg * 32;
        #pragma unroll
        for (int kk = 0; kk < 16; ++kk) {
            wx0[kk] = W_ih[(size_t)R0 * Cn + kbx + kk];
            wx1[kk] = W_ih[(size_t)R1 * Cn + kbx + kk];
        }
        #pragma unroll
        for (int kk = 0; kk < 32; ++kk) {
            wh0[kk] = W_hh[(size_t)R0 * Hn + kbh + kk];
            wh1[kk] = W_hh[(size_t)R1 * Hn + kbh + kk];
        }
    }
    {
        const float* wr = W_skip + (size_t)(u0 + sr) * Hn;
        #pragma unroll
        for (int c = 0; c < 4; ++c)
            *(float4*)&s_wsk[sr][c * 64 + su * 4] = *(const float4*)&wr[c * 64 + su * 4];
        if (tid < 64) {
            int R = (tid >> 4) * Hn + u0 + (tid & 15);
            s_bias[tid] = b_ih[R] + b_hh[R];
        }
        if (tid < 16) s_bskip[tid] = b_skip[u0 + tid];
    }
    float c_reg = c0[u0 + su];

    // prefetch x[t=0]
    float4 xp0, xp1;
    {
        const float* xr = x + (size_t)(row0 + sr) * (Tn * Cn);
        xp0 = *(const float4*)&xr[su * 4];
        xp1 = *(const float4*)&xr[64 + su * 4];
    }
    __syncthreads();

    for (int t = 0; t < Tn; ++t) {
        const bool do_ring = (t >= WIN - 1) && (t < Tn - 1);

        // ================= PHASE A: no h_t needed =================
        // A1: prefetch peer flags (checked in phase B)
        int fpre = 0;
        if (tid < NUG)
            fpre = __hip_atomic_load(&g_flag[rg][tid].v, RLX, AGENT);

        // A2: stage x_t (from regs), issue x(t+1) prefetch + ring loads
        *(float4*)&s_in[sr][su * 4]      = xp0;
        *(float4*)&s_in[sr][64 + su * 4] = xp1;
        if (t + 1 < Tn) {
            const float* xr = x + (size_t)(row0 + sr) * (Tn * Cn) + (size_t)(t + 1) * Cn;
            xp0 = *(const float4*)&xr[su * 4];
            xp1 = *(const float4*)&xr[64 + su * 4];
        }
        float rv[16];
        if (do_ring) {
            const float* hsrc = outp + (size_t)(row0 + sr) * (Tn * Hn)
                                     + (size_t)(t - (WIN - 1)) * Hn;
            #pragma unroll
            for (int c = 0; c < 16; ++c)
                rv[c] = __hip_atomic_load((float*)&hsrc[su + 16 * c], RLX, AGENT);
        }
        __syncthreads();   // x staged

        // A3: x-part GEMM (k < 128): init accumulators
        float a0[RPB], a1[RPB];
        #pragma unroll
        for (int r = 0; r < RPB; ++r) { a0[r] = 0.f; a1[r] = 0.f; }
        {
            const int kb = kg * 16;
            #pragma unroll
            for (int kk = 0; kk < 16; kk += 4) {
                #pragma unroll
                for (int r = 0; r < RPB; ++r) {
                    float4 hv4 = *(const float4*)&s_in[r][kb + kk];
                    a0[r] = fmaf(hv4.x, wx0[kk],     a0[r]);
                    a0[r] = fmaf(hv4.y, wx0[kk + 1], a0[r]);
                    a0[r] = fmaf(hv4.z, wx0[kk + 2], a0[r]);
                    a0[r] = fmaf(hv4.w, wx0[kk + 3], a0[r]);
                    a1[r] = fmaf(hv4.x, wx1[kk],     a1[r]);
                    a1[r] = fmaf(hv4.y, wx1[kk + 1], a1[r]);
                    a1[r] = fmaf(hv4.z, wx1[kk + 2], a1[r]);
                    a1[r] = fmaf(hv4.w, wx1[kk + 3], a1[r]);
                }
            }
        }

        // A4: skip pre-GEMM for THIS step's publish: sk = h_{t-23} @ W_skip^T
        float sk = 0.f;
        if (do_ring) {
            #pragma unroll
            for (int c = 0; c < 16; ++c)
                s_h24[sr][su + 16 * c] = rv[c];
            __syncthreads();
            #pragma unroll
            for (int k = 0; k < Hn; k += 4) {
                float4 hv4 = *(const float4*)&s_h24[sr][k];
                float4 wv4 = *(const float4*)&s_wsk[su][k];
                sk = fmaf(hv4.x, wv4.x, sk);
                sk = fmaf(hv4.y, wv4.y, sk);
                sk = fmaf(hv4.z, wv4.z, sk);
                sk = fmaf(hv4.w, wv4.w, sk);
            }
        }

        // ================= PHASE B: critical path =================
        // B1: wait for peers (common case: fpre already >= t)
        if (tid < NUG) {
            int f = fpre;
            while (f < t)
                f = __hip_atomic_load(&g_flag[rg][tid].v, RLX, AGENT);
        }
        __syncthreads();

        // B2: load h_in(t) from MALL, stage to LDS
        {
            float hv[16];
            float* hxs = &g_hx[t & 1][row0 + sr][0];
            #pragma unroll
            for (int c = 0; c < 16; ++c)
                hv[c] = __hip_atomic_load(&hxs[su + 16 * c], RLX, AGENT);
            #pragma unroll
            for (int c = 0; c < 16; ++c)
                s_in[sr][Cn + su + 16 * c] = hv[c];
        }
        __syncthreads();

        // B3: h-part GEMM (k = 128..383), accumulate into a0/a1
        {
            const int kb = Cn + kg * 32;
            #pragma unroll
            for (int kk = 0; kk < 32; kk += 4) {
                #pragma unroll
                for (int r = 0; r < RPB; ++r) {
                    float4 hv4 = *(const float4*)&s_in[r][kb + kk];
                    a0[r] = fmaf(hv4.x, wh0[kk],     a0[r]);
                    a0[r] = fmaf(hv4.y, wh0[kk + 1], a0[r]);
                    a0[r] = fmaf(hv4.z, wh0[kk + 2], a0[r]);
                    a0[r] = fmaf(hv4.w, wh0[kk + 3], a0[r]);
                    a1[r] = fmaf(hv4.x, wh1[kk],     a1[r]);
                    a1[r] = fmaf(hv4.y, wh1[kk + 1], a1[r]);
                    a1[r] = fmaf(hv4.z, wh1[kk + 2], a1[r]);
                    a1[r] = fmaf(hv4.w, wh1[kk + 3], a1[r]);
                }
            }
        }

        // B4: reduce 8 k-partials
        #pragma unroll
        for (int r = 0; r < RPB; ++r) {
            a0[r] += __shfl_xor(a0[r], 32, 64);
            a1[r] += __shfl_xor(a1[r], 32, 64);
        }
        if ((tid & 32) == 0) {
            #pragma unroll
            for (int r = 0; r < RPB; ++r) {
                s_red[wv][nq][r * 2]     = a0[r];
                s_red[wv][nq][r * 2 + 1] = a1[r];
            }
        }
        __syncthreads();

        // B5: cell update: thread (sr, su) owns (row row0+sr, unit u0+su)
        float gate[4];
        #pragma unroll
        for (int g = 0; g < 4; ++g) {
            int wl = g * 16 + su;
            int q = wl >> 1, j = wl & 1;
            float v = s_bias[wl];
            v += s_red[0][q][sr * 2 + j];
            v += s_red[1][q][sr * 2 + j];
            v += s_red[2][q][sr * 2 + j];
            v += s_red[3][q][sr * 2 + j];
            gate[g] = v;
        }
        float si = 1.f / (1.f + expf(-gate[0]));
        float sf = 1.f / (1.f + expf(-gate[1]));
        float gt = tanhf(gate[2]);
        float so = 1.f / (1.f + expf(-gate[3]));
        c_reg = sf * c_reg + si * gt;
        float hn = so * tanhf(c_reg);
        __hip_atomic_store(&outp[(size_t)(row0 + sr) * (Tn * Hn) + (size_t)t * Hn + u0 + su],
                           hn, RLX, AGENT);

        // B6: publish h_in(t+1) = hn + precomputed skip
        if (t < Tn - 1) {
            float hin = hn;
            if (do_ring) hin += sk + s_bskip[su];
            __hip_atomic_store(&g_hx[(t + 1) & 1][row0 + sr][u0 + su], hin, RLX, AGENT);
            asm volatile("s_waitcnt vmcnt(0)" ::: "memory");
            __syncthreads();
            if (tid == 0)
                __hip_atomic_store(&g_flag[rg][ug].v, t + 1, RLX, AGENT);
        } else {
            hbuf[(size_t)(row0 + sr) * Hn + u0 + su] = hn;
            cbuf[(size_t)(row0 + sr) * Hn + u0 + su] = c_reg;
        }
    }
}

extern "C" void kernel_launch(void* const* d_in, const int* in_sizes, int n_in,
                              void* d_out, int out_size, void* d_ws, size_t ws_size,
                              hipStream_t stream)
{
    const float* x      = (const float*)d_in[0];
    const float* W_ih   = (const float*)d_in[1];
    const float* W_hh   = (const float*)d_in[2];
    const float* b_ih   = (const float*)d_in[3];
    const float* b_hh   = (const float*)d_in[4];
    const float* W_skip = (const float*)d_in[5];
    const float* b_skip = (const float*)d_in[6];
    const float* h0     = (const float*)d_in[7];
    const float* c0     = (const float*)d_in[8];

    float* outp = (float*)d_out;
    float* hbuf = outp + (size_t)Bn * Tn * Hn;
    float* cbuf = hbuf + (size_t)Bn * Hn;

    init_sync<<<256, 256, 0, stream>>>(h0);
    lstm_persist<<<256, 256, 0, stream>>>(x, W_ih, W_hh, b_ih, b_hh,
                                          W_skip, b_skip, c0, outp, hbuf, cbuf);
}

// Round 5
// 6700.198 us; speedup vs baseline: 8.9009x; 1.1617x over previous
//
#include <hip/hip_runtime.h>
#include <cstddef>

#define Bn  256
#define Tn  1024
#define Cn  128
#define Hn  256
#define WIN 24

#define NRG 16   // row groups
#define NUG 16   // unit groups
#define RPB 16   // rows per block
#define UPB 16   // units per block

#define AGENT __HIP_MEMORY_SCOPE_AGENT
#define RLX   __ATOMIC_RELAXED

typedef __attribute__((ext_vector_type(8))) short bf16x8;   // 8 bf16 = 4 VGPR (guide §3)
typedef __attribute__((ext_vector_type(4))) float f32x4;

#define MFMA(a, b, c) __builtin_amdgcn_mfma_f32_16x16x32_bf16((a), (b), (c), 0, 0, 0)

struct __align__(64) Flag { int v; int pad[15]; };
__device__ Flag  g_flag[NRG][NUG];
__device__ float g_hx[2][Bn][Hn];   // h_in exchange, double-buffered by t parity

__device__ inline unsigned short f2bf(float f) {
    union { float f; unsigned u; } v; v.f = f;
    unsigned r = (v.u + 0x7FFF + ((v.u >> 16) & 1)) >> 16;   // RNE
    return (unsigned short)r;
}
__device__ inline float bf2f(unsigned short b) {
    union { unsigned u; float f; } v; v.u = (unsigned)b << 16;
    return v.f;
}
// split 8 fp32 -> bf16 hi + bf16 lo (x ~= hi + lo, residual ~2^-18 rel)
__device__ inline void split8(const float* s, bf16x8& hi, bf16x8& lo) {
    #pragma unroll
    for (int e = 0; e < 8; ++e) {
        unsigned short h = f2bf(s[e]);
        float r = s[e] - bf2f(h);
        hi[e] = (short)h;
        lo[e] = (short)f2bf(r);
    }
}

__global__ __launch_bounds__(256) void init_sync(const float* __restrict__ h0) {
    int i = blockIdx.x * 256 + threadIdx.x;       // 0 .. 65535
    g_hx[0][i >> 8][i & 255] = h0[i & 255];       // h_in for t=0 is h0 (mask=0)
    if (i < NRG * NUG) g_flag[i >> 4][i & 15].v = 0;
}

__global__ __launch_bounds__(512, 1) void lstm_persist(
    const float* __restrict__ x,
    const float* __restrict__ W_ih, const float* __restrict__ W_hh,
    const float* __restrict__ b_ih, const float* __restrict__ b_hh,
    const float* __restrict__ W_skip, const float* __restrict__ b_skip,
    const float* __restrict__ c0,
    float* __restrict__ outp, float* __restrict__ hbuf, float* __restrict__ cbuf)
{
    extern __shared__ char s_dynpad[];    // launch-time pad: forces LDS>80KB -> 1 block/CU
    (void)s_dynpad;

    // A-operand fragments, per-lane layout: m = lane&15, k = (lane>>4)*8 + e
    // (same assumed k-mapping used for B frags -> any HW k-permutation cancels)
    __shared__ bf16x8 s_ga[2][12][64];    // [hi/lo][kstep 0..3 = x, 4..11 = h][lane]
    __shared__ bf16x8 s_sa[2][8][64];     // skip A frags (h_{t-23}), kstep 0..7
    __shared__ f32x4  s_red[4][64];       // kh=1 partial gates, per gate-tile
    __shared__ float  s_cell[4][64][4];   // full gate frags per gate, scalar-indexed
    __shared__ float  s_sk[8][64][4];     // skip partials per wave
    __shared__ float  s_bias[64];
    __shared__ float  s_bskip[UPB];

    const int tid = threadIdx.x;
    // XCD swizzle (kept from r4): each row-group's 16 blocks on one XCD
    const int xcd = blockIdx.x & 7, slot = blockIdx.x >> 3;
    const int rg = (xcd << 1) | (slot >> 4), ug = slot & 15;
    const int row0 = rg * RPB, u0 = ug * UPB;

    const int w    = tid >> 6;            // wave 0..7
    const int lane = tid & 63;
    const int g    = w & 3;               // gate tile (torch order i,f,g,o)
    const int kh   = w >> 2;              // K-half
    const int nl   = lane & 15;           // B n-index (unit within block)
    const int kq   = lane >> 4;           // k-quad within kstep

    // ---- once: B-operand weight fragments into registers ----
    bf16x8 whh_hi[4], whh_lo[4], wx_hi[2], wx_lo[2], ws_hi, ws_lo;
    {
        const int Rg = g * Hn + u0 + nl;              // gate-row in [0,1024)
        const float* wr = W_hh + (size_t)Rg * Hn;
        #pragma unroll
        for (int j = 0; j < 4; ++j) {
            float tmp[8];
            const int k = (kh * 4 + j) * 32 + kq * 8;
            #pragma unroll
            for (int e = 0; e < 8; ++e) tmp[e] = wr[k + e];
            split8(tmp, whh_hi[j], whh_lo[j]);
        }
        const float* wr2 = W_ih + (size_t)Rg * Cn;
        #pragma unroll
        for (int j = 0; j < 2; ++j) {
            float tmp[8];
            const int k = (kh * 2 + j) * 32 + kq * 8;
            #pragma unroll
            for (int e = 0; e < 8; ++e) tmp[e] = wr2[k + e];
            split8(tmp, wx_hi[j], wx_lo[j]);
        }
        const float* wr3 = W_skip + (size_t)(u0 + nl) * Hn;
        float tmp[8];
        const int k = w * 32 + kq * 8;
        #pragma unroll
        for (int e = 0; e < 8; ++e) tmp[e] = wr3[k + e];
        split8(tmp, ws_hi, ws_lo);
    }
    if (tid < 64)  s_bias[tid]  = b_ih[(tid >> 4) * Hn + u0 + (tid & 15)]
                                + b_hh[(tid >> 4) * Hn + u0 + (tid & 15)];
    if (tid < 16)  s_bskip[tid] = b_skip[u0 + tid];

    float c_reg = (tid < 256) ? c0[u0 + (tid & 15)] : 0.f;
    __syncthreads();

    for (int t = 0; t < Tn; ++t) {
        const bool do_ring = (t >= WIN - 1) && (t < Tn - 1);

        // ================= PHASE A (no h_t dependency) =================
        int fpre = 0;
        if (tid < NUG)
            fpre = __hip_atomic_load(&g_flag[rg][tid].v, RLX, AGENT);

        // A1: stage x_t fragments (ksteps 0..3); waves 0-3 only
        if (tid < 256) {
            const int ks = tid >> 6, l = tid & 63;
            const int m = l & 15, kq2 = l >> 4;
            const float* src = x + (size_t)(row0 + m) * (Tn * Cn) + (size_t)t * Cn
                                 + ks * 32 + kq2 * 8;
            float tmp[8];
            #pragma unroll
            for (int e = 0; e < 8; ++e) tmp[e] = src[e];
            bf16x8 hi, lo; split8(tmp, hi, lo);
            s_ga[0][ks][l] = hi; s_ga[1][ks][l] = lo;
        }
        // A2: stage skip fragments h_{t-23} (ring = outp), all 8 ksteps
        if (do_ring) {
            const int ks = tid >> 6, l = tid & 63;
            const int m = l & 15, kq2 = l >> 4;
            const float* src = outp + (size_t)(row0 + m) * (Tn * Hn)
                                    + (size_t)(t - (WIN - 1)) * Hn + ks * 32 + kq2 * 8;
            float tmp[8];
            #pragma unroll
            for (int e = 0; e < 8; ++e)
                tmp[e] = __hip_atomic_load((float*)&src[e], RLX, AGENT);
            bf16x8 hi, lo; split8(tmp, hi, lo);
            s_sa[0][ks][l] = hi; s_sa[1][ks][l] = lo;
        }
        __syncthreads();   // (1) frags staged

        // A3: x-part MFMA (acc init) + skip MFMA
        f32x4 acc = {0.f, 0.f, 0.f, 0.f};
        #pragma unroll
        for (int j = 0; j < 2; ++j) {
            const int ks = kh * 2 + j;
            bf16x8 ah = s_ga[0][ks][lane], al = s_ga[1][ks][lane];
            acc = MFMA(ah, wx_hi[j], acc);
            acc = MFMA(ah, wx_lo[j], acc);
            acc = MFMA(al, wx_hi[j], acc);
        }
        if (do_ring) {
            f32x4 ask = {0.f, 0.f, 0.f, 0.f};
            bf16x8 ah = s_sa[0][w][lane], al = s_sa[1][w][lane];
            ask = MFMA(ah, ws_hi, ask);
            ask = MFMA(ah, ws_lo, ask);
            ask = MFMA(al, ws_hi, ask);
            *(f32x4*)&s_sk[w][lane][0] = ask;
        }

        // ================= PHASE B (critical path) =================
        // B1: wait for all 16 peers' h_in(t)
        if (tid < NUG) {
            int f = fpre;
            while (f < t)
                f = __hip_atomic_load(&g_flag[rg][tid].v, RLX, AGENT);
        }
        __syncthreads();   // (2)

        // B2: stage h_in fragments (ksteps 4..11), one (kstep,lane) per thread
        {
            const int ks = tid >> 6, l = tid & 63;
            const int m = l & 15, kq2 = l >> 4;
            const float* src = &g_hx[t & 1][row0 + m][ks * 32 + kq2 * 8];
            float tmp[8];
            #pragma unroll
            for (int e = 0; e < 8; ++e)
                tmp[e] = __hip_atomic_load((float*)&src[e], RLX, AGENT);
            bf16x8 hi, lo; split8(tmp, hi, lo);
            s_ga[0][4 + ks][l] = hi; s_ga[1][4 + ks][l] = lo;
        }
        __syncthreads();   // (3)

        // B3: h-part MFMA
        #pragma unroll
        for (int j = 0; j < 4; ++j) {
            const int ks = 4 + kh * 4 + j;
            bf16x8 ah = s_ga[0][ks][lane], al = s_ga[1][ks][lane];
            acc = MFMA(ah, whh_hi[j], acc);
            acc = MFMA(ah, whh_lo[j], acc);
            acc = MFMA(al, whh_hi[j], acc);
        }

        // B4: reduce the two K-halves
        if (kh == 1) s_red[g][lane] = acc;
        __syncthreads();   // (4)
        if (kh == 0) {
            f32x4 o = s_red[g][lane];
            acc = acc + o;
            *(f32x4*)&s_cell[g][lane][0] = acc;
        }
        __syncthreads();   // (5)

        // B5: cell update; thread tid<256 owns (row m, unit ul)
        if (tid < 256) {
            const int m = tid >> 4, ul = tid & 15;
            const int li = ((m >> 2) << 4) | ul, r = m & 3;   // D: m=(lane>>4)*4+reg, n=lane&15
            float gv[4];
            #pragma unroll
            for (int g2 = 0; g2 < 4; ++g2)
                gv[g2] = s_cell[g2][li][r] + s_bias[g2 * 16 + ul];
            float si = 1.f / (1.f + expf(-gv[0]));
            float sf = 1.f / (1.f + expf(-gv[1]));
            float gt = tanhf(gv[2]);
            float so = 1.f / (1.f + expf(-gv[3]));
            c_reg = sf * c_reg + si * gt;
            float hn = so * tanhf(c_reg);
            __hip_atomic_store(&outp[(size_t)(row0 + m) * (Tn * Hn) + (size_t)t * Hn + u0 + ul],
                               hn, RLX, AGENT);
            if (t < Tn - 1) {
                float hin = hn;
                if (do_ring) {
                    float sk = 0.f;
                    #pragma unroll
                    for (int w2 = 0; w2 < 8; ++w2) sk += s_sk[w2][li][r];
                    hin += sk + s_bskip[ul];
                }
                __hip_atomic_store(&g_hx[(t + 1) & 1][row0 + m][u0 + ul], hin, RLX, AGENT);
            } else {
                hbuf[(size_t)(row0 + m) * Hn + u0 + ul] = hn;
                cbuf[(size_t)(row0 + m) * Hn + u0 + ul] = c_reg;
            }
        }

        // B6: drain publishes to coherence point, then release flag
        if (t < Tn - 1) {
            asm volatile("s_waitcnt vmcnt(0)" ::: "memory");
            __syncthreads();   // (6)
            if (tid == 0)
                __hip_atomic_store(&g_flag[rg][ug].v, t + 1, RLX, AGENT);
        }
    }
}

extern "C" void kernel_launch(void* const* d_in, const int* in_sizes, int n_in,
                              void* d_out, int out_size, void* d_ws, size_t ws_size,
                              hipStream_t stream)
{
    const float* x      = (const float*)d_in[0];
    const float* W_ih   = (const float*)d_in[1];
    const float* W_hh   = (const float*)d_in[2];
    const float* b_ih   = (const float*)d_in[3];
    const float* b_hh   = (const float*)d_in[4];
    const float* W_skip = (const float*)d_in[5];
    const float* b_skip = (const float*)d_in[6];
    const float* h0     = (const float*)d_in[7];
    const float* c0     = (const float*)d_in[8];

    float* outp = (float*)d_out;
    float* hbuf = outp + (size_t)Bn * Tn * Hn;
    float* cbuf = hbuf + (size_t)Bn * Hn;

    init_sync<<<256, 256, 0, stream>>>(h0);
    // 40KB dynamic-LDS pad: static (~58KB) + 40KB > 80KB -> exactly 1 block/CU
    lstm_persist<<<256, 512, 40960, stream>>>(x, W_ih, W_hh, b_ih, b_hh,
                                              W_skip, b_skip, c0, outp, hbuf, cbuf);
}